// Round 15
// baseline (595.254 us; speedup 1.0000x reference)
//
#include <hip/hip_runtime.h>
#include <math.h>

typedef unsigned int uint;
typedef unsigned short ushort;

#define HIDF 256
#define HD4 1024
#define NHEAD 4
#define N_LINK 2000
#define N_FLOW 30000
#define N_PATH 50000
#define NEDGE 120000
#define N_CVT 26
#define NPP (N_PATH + 1)
#define NSCAN (2 * NPP)
#define NB2 ((NSCAN + 1023) / 1024)  // 98
#define RCAP 8192  // conv2 zs chunk rows: 16.8MB -> stays L3-hot between gemm write and gather read

// ---- bf16 helpers (bf16 = high 16 bits of fp32) ----
__device__ inline float bf_lo(uint u) { return __uint_as_float(u << 16); }
__device__ inline float bf_hi(uint u) { return __uint_as_float(u & 0xffff0000u); }
__device__ inline float ldb(const ushort* p) { return __uint_as_float(((uint)*p) << 16); }
__device__ inline ushort f2b(float f) {  // round-to-nearest-even
    uint x = __float_as_uint(f);
    return (ushort)((x + 0x7fffu + ((x >> 16) & 1u)) >> 16);
}
__device__ inline void unpack8(uint4 v, float* f) {
    f[0] = bf_lo(v.x); f[1] = bf_hi(v.x);
    f[2] = bf_lo(v.y); f[3] = bf_hi(v.y);
    f[4] = bf_lo(v.z); f[5] = bf_hi(v.z);
    f[6] = bf_lo(v.w); f[7] = bf_hi(v.w);
}

typedef __attribute__((ext_vector_type(8))) short bf16x8;
typedef __attribute__((ext_vector_type(4))) float f32x4;

// ---------------------------------------------------------------------------
// dtype detect: probe even-index ushorts of attn_l1. flag: 1 = bf16, 0 = fp32.
// ---------------------------------------------------------------------------
__global__ void detect_dtype(const ushort* __restrict__ probe, int* __restrict__ flag) {
    int lane = threadIdx.x;  // 0..63
    uint u = probe[lane * 2];
    int e = (u >> 7) & 0xFF;
    bool sane = (u != 0u) && (e <= 0x4F);
    unsigned long long m = __ballot(sane);
    if (lane == 0) *flag = (__popcll(m) >= 48) ? 1 : 0;
}

// ---------------------------------------------------------------------------
// batched input conversion into bf16 arena (passthrough when already bf16)
// ---------------------------------------------------------------------------
struct CvtArgs {
    const void* src[N_CVT];
    int off[N_CVT];
    int sz[N_CVT];
};

__global__ __launch_bounds__(256) void convert_inputs(CvtArgs a, ushort* __restrict__ dst,
                                                      const int* __restrict__ flag) {
    int i = blockIdx.y;
    int idx = blockIdx.x * 256 + threadIdx.x;
    if (idx >= a.sz[i]) return;
    ushort v;
    if (*flag) v = ((const ushort*)a.src[i])[idx];
    else       v = f2b(((const float*)a.src[i])[idx]);
    dst[a.off[i] + idx] = v;
}

// sentinel: broadcast ws_MB so a too-small workspace reveals its size
__global__ void sentinel_fill(void* out, int n, float val, const int* flag) {
    int i = blockIdx.x * 256 + threadIdx.x;
    if (i >= n) return;
    if (*flag) ((ushort*)out)[i] = f2b(val);
    else       ((float*)out)[i] = val;
}

// ---------------------------------------------------------------------------
// prep_fold: one WAVE per output scalar (4100 waves).
// ---------------------------------------------------------------------------
struct PrepArgs {
    const ushort* fc[5];
    const ushort* at[5];
    float* out[5];
};

__global__ __launch_bounds__(256) void prep_fold(PrepArgs pa) {
    int w = blockIdx.x * 4 + (threadIdx.x >> 6);
    int lane = threadIdx.x & 63;
    int m, k, h;
    if (w < 4096) {
        m = w >> 10;
        k = (w >> 2) & 255;
        h = w & 3;
    } else if (w < 4100) {
        m = 4;
        k = 0;
        h = w - 4096;
    } else {
        return;
    }
    size_t fbase = (m == 4) ? 0 : (size_t)k * HD4;
    uint2 fv = *(const uint2*)(pa.fc[m] + fbase + h * HIDF + lane * 4);
    uint2 av = *(const uint2*)(pa.at[m] + h * HIDF + lane * 4);
    float s = bf_lo(fv.x) * bf_lo(av.x) + bf_hi(fv.x) * bf_hi(av.x) +
              bf_lo(fv.y) * bf_lo(av.y) + bf_hi(fv.y) * bf_hi(av.y);
#pragma unroll
    for (int off = 32; off >= 1; off >>= 1) s += __shfl_down(s, off, 64);
    if (lane == 0) {
        if (m < 4) pa.out[m][k * NHEAD + h] = s;
        else       pa.out[4][h] = s;
    }
}

// ---------------------------------------------------------------------------
// batched 32x32 transpose: d[n*K+k] = s1[k*N+n] (+ s2[k*N+n] if s2)
// ---------------------------------------------------------------------------
struct TJobs {
    const ushort* s1[6];
    const ushort* s2[6];
    ushort* d[6];
    int K[6];
    int N[6];
};

__global__ __launch_bounds__(256) void transpose_batch(TJobs tj) {
    int j = blockIdx.y;
    int K = tj.K[j], N = tj.N[j];
    int tilesx = N >> 5;
    if ((int)blockIdx.x >= tilesx * (K >> 5)) return;
    int n0 = (blockIdx.x % tilesx) * 32, k0 = (blockIdx.x / tilesx) * 32;
    const ushort* s1 = tj.s1[j];
    const ushort* s2 = tj.s2[j];
    ushort* dst = tj.d[j];
    __shared__ ushort tile[32][33];
    int jj = threadIdx.x & 31, i0 = threadIdx.x >> 5;
    for (int i = i0; i < 32; i += 8) {
        size_t idx = (size_t)(k0 + i) * N + n0 + jj;
        float v = ldb(s1 + idx);
        if (s2) v += ldb(s2 + idx);
        tile[i][jj] = f2b(v);
    }
    __syncthreads();
    for (int i = i0; i < 32; i += 8) dst[(size_t)(n0 + i) * K + k0 + jj] = tile[jj][i];
}

// ---------------------------------------------------------------------------
// proj v2: 8 rows/block, 8 cols/thread, uint4 loads/stores throughout.
// ---------------------------------------------------------------------------
template <int K>
__device__ inline void proj_body(const ushort* __restrict__ X, const ushort* __restrict__ W,
                                 const ushort* __restrict__ bias, ushort* __restrict__ Y, int rowblk) {
    int t = threadIdx.x;
    int r = t >> 5;            // 0..7 row within the 8-row group
    int c8 = (t & 31) * 8;     // col base
    int i = rowblk * 8 + r;
    float x[K];
    const uint4* xp = (const uint4*)(X + (size_t)i * K);
    unpack8(xp[0], x);
    if (K == 16) unpack8(xp[1], x + 8);
    float s[8];
    unpack8(*(const uint4*)(bias + c8), s);
#pragma unroll
    for (int k = 0; k < K; ++k) {
        float w[8];
        unpack8(*(const uint4*)(W + k * HIDF + c8), w);
        float xv = x[k];
#pragma unroll
        for (int j = 0; j < 8; ++j) s[j] += xv * w[j];
    }
    uint uo[4];
#pragma unroll
    for (int j = 0; j < 4; ++j) {
        float a = fmaxf(s[2 * j], 0.f), b = fmaxf(s[2 * j + 1], 0.f);
        uo[j] = (uint)f2b(a) | ((uint)f2b(b) << 16);
    }
    *(uint4*)(Y + (size_t)i * HIDF + c8) = make_uint4(uo[0], uo[1], uo[2], uo[3]);
}

__global__ __launch_bounds__(256) void proj_all(const ushort* X0, const ushort* W0, const ushort* b0, ushort* Y0,
                                                const ushort* X1, const ushort* W1, const ushort* b1, ushort* Y1,
                                                const ushort* X2, const ushort* W2, const ushort* b2, ushort* Y2) {
    int b = blockIdx.x;
    const int BL = N_LINK / 8, BF = N_FLOW / 8;
    if (b < BL) proj_body<8>(X0, W0, b0, Y0, b);
    else if (b < BL + BF) proj_body<16>(X1, W1, b1, Y1, b - BL);
    else proj_body<8>(X2, W2, b2, Y2, b - BL - BF);
}

// ---------------------------------------------------------------------------
// MFMA bf16 GEMM v2 (round-9 config): 64x128 block, 4 waves of 64x32, BK=32,
// double-buffered LDS, ONE barrier per K-iter.  (used for the zs GEMMs)
// ---------------------------------------------------------------------------
#define GTM 64
#define GTN 128
#define GTK 32
#define GPAD 40

#define LOAD_TILE(t)                                                          \
    {                                                                         \
        const ushort* A;                                                      \
        const ushort* BT;                                                     \
        int K, k0;                                                            \
        if ((t) < nt1) { A = A1; BT = B1T; K = K1; k0 = (t)*GTK; }            \
        else           { A = A2; BT = B2T; K = K2; k0 = ((t)-nt1) * GTK; }    \
        av = (bm + ar < M) ? *(const uint4*)(A + (size_t)(bm + ar) * K + k0 + aq * 8) : z4; \
        bv0 = *(const uint4*)(BT + (size_t)(bn + ar) * K + k0 + aq * 8);      \
        bv1 = *(const uint4*)(BT + (size_t)(bn + ar + 64) * K + k0 + aq * 8); \
    }

#define STORE_TILE(b)                                                         \
    {                                                                         \
        *(uint4*)&As[b][ar][aq * 8] = av;                                     \
        *(uint4*)&Bs[b][ar][aq * 8] = bv0;                                    \
        *(uint4*)&Bs[b][ar + 64][aq * 8] = bv1;                               \
    }

__global__ __launch_bounds__(256) void gemm_mfma(const ushort* __restrict__ A1, const ushort* __restrict__ B1T, int K1,
                                                 const ushort* __restrict__ A2, const ushort* __restrict__ B2T, int K2,
                                                 const ushort* __restrict__ Dadd, const ushort* __restrict__ bias,
                                                 int do_relu, ushort* __restrict__ C, int M, int N) {
    __shared__ __align__(16) ushort As[2][GTM][GPAD];
    __shared__ __align__(16) ushort Bs[2][GTN][GPAD];

    int tid = threadIdx.x;
    int lane = tid & 63, wave = tid >> 6;
    int quad = lane >> 4, l16 = lane & 15;
    int wn = wave * 32;
    int bm = blockIdx.y * GTM, bn = blockIdx.x * GTN;

    f32x4 acc[4][2];
    f32x4 zf = {0.f, 0.f, 0.f, 0.f};
#pragma unroll
    for (int i = 0; i < 4; ++i) {
        acc[i][0] = zf;
        acc[i][1] = zf;
    }

    int ar = tid >> 2, aq = tid & 3;
    uint4 av, bv0, bv1;
    uint4 z4 = {0, 0, 0, 0};

    int nt1 = K1 / GTK;
    int ntot = nt1 + K2 / GTK;

    LOAD_TILE(0);
    STORE_TILE(0);
    __syncthreads();

    for (int t = 0; t < ntot; ++t) {
        int cur = t & 1, nxt = cur ^ 1;
        if (t + 1 < ntot) LOAD_TILE(t + 1);

        bf16x8 af[4], bf[2];
#pragma unroll
        for (int mt = 0; mt < 4; ++mt) af[mt] = *(const bf16x8*)&As[cur][mt * 16 + l16][quad * 8];
#pragma unroll
        for (int ct = 0; ct < 2; ++ct) bf[ct] = *(const bf16x8*)&Bs[cur][wn + ct * 16 + l16][quad * 8];
#pragma unroll
        for (int mt = 0; mt < 4; ++mt)
#pragma unroll
            for (int ct = 0; ct < 2; ++ct)
                acc[mt][ct] = __builtin_amdgcn_mfma_f32_16x16x32_bf16(af[mt], bf[ct], acc[mt][ct], 0, 0, 0);

        if (t + 1 < ntot) STORE_TILE(nxt);
        __syncthreads();
    }

#pragma unroll
    for (int mt = 0; mt < 4; ++mt) {
#pragma unroll
        for (int ct = 0; ct < 2; ++ct) {
            int col = bn + wn + ct * 16 + l16;
#pragma unroll
            for (int rg = 0; rg < 4; ++rg) {
                int row = bm + mt * 16 + quad * 4 + rg;
                if (row >= M) continue;
                float v = acc[mt][ct][rg];
                if (Dadd) v += ldb(Dadd + (size_t)row * N + col);
                if (bias) v += ldb(bias + col);
                if (do_relu) v = fmaxf(v, 0.f);
                C[(size_t)row * N + col] = f2b(v);
            }
        }
    }
}

// ---------------------------------------------------------------------------
// MFMA bf16 GEMM 64x64 (high-occupancy, N=256 GEMMs) with VECTORIZED epilogue
// via LDS-aliased fp32 staging tile.
// ---------------------------------------------------------------------------
#define LOAD_T64(t)                                                           \
    {                                                                         \
        const ushort* A;                                                      \
        const ushort* BT;                                                     \
        int K, k0;                                                            \
        if ((t) < nt1) { A = A1; BT = B1T; K = K1; k0 = (t)*GTK; }            \
        else           { A = A2; BT = B2T; K = K2; k0 = ((t)-nt1) * GTK; }    \
        av = (bm + ar < M) ? *(const uint4*)(A + (size_t)(bm + ar) * K + k0 + aq * 8) : z4; \
        bv = *(const uint4*)(BT + (size_t)(bn + ar) * K + k0 + aq * 8);       \
    }

#define STORE_T64(b)                                                          \
    {                                                                         \
        *(uint4*)&As[b][ar][aq * 8] = av;                                     \
        *(uint4*)&Bs[b][ar][aq * 8] = bv;                                     \
    }

__global__ __launch_bounds__(256) void gemm_mfma64(const ushort* __restrict__ A1, const ushort* __restrict__ B1T, int K1,
                                                   const ushort* __restrict__ A2, const ushort* __restrict__ B2T, int K2,
                                                   const ushort* __restrict__ Dadd, const ushort* __restrict__ bias,
                                                   int do_relu, ushort* __restrict__ C, int M, int N) {
    __shared__ __align__(16) char smem[20480];
    auto As = (ushort(*)[64][GPAD])smem;            // [2][64][40]
    auto Bs = (ushort(*)[64][GPAD])(smem + 10240);  // [2][64][40]
    auto ct = (float(*)[68])smem;                   // [64][68]

    int tid = threadIdx.x;
    int lane = tid & 63, wave = tid >> 6;
    int quad = lane >> 4, l16 = lane & 15;
    int wm = (wave >> 1) * 32, wn = (wave & 1) * 32;
    int bm = blockIdx.y * 64, bn = blockIdx.x * 64;

    f32x4 acc[2][2];
    f32x4 zf = {0.f, 0.f, 0.f, 0.f};
    acc[0][0] = zf; acc[0][1] = zf; acc[1][0] = zf; acc[1][1] = zf;

    int ar = tid >> 2, aq = tid & 3;
    uint4 av, bv;
    uint4 z4 = {0, 0, 0, 0};

    int nt1 = K1 / GTK;
    int ntot = nt1 + K2 / GTK;

    LOAD_T64(0);
    STORE_T64(0);
    __syncthreads();

    for (int t = 0; t < ntot; ++t) {
        int cur = t & 1, nxt = cur ^ 1;
        if (t + 1 < ntot) LOAD_T64(t + 1);

        bf16x8 af[2], bf[2];
#pragma unroll
        for (int mt = 0; mt < 2; ++mt) af[mt] = *(const bf16x8*)&As[cur][wm + mt * 16 + l16][quad * 8];
#pragma unroll
        for (int nt = 0; nt < 2; ++nt) bf[nt] = *(const bf16x8*)&Bs[cur][wn + nt * 16 + l16][quad * 8];
#pragma unroll
        for (int mt = 0; mt < 2; ++mt)
#pragma unroll
            for (int nt = 0; nt < 2; ++nt)
                acc[mt][nt] = __builtin_amdgcn_mfma_f32_16x16x32_bf16(af[mt], bf[nt], acc[mt][nt], 0, 0, 0);

        if (t + 1 < ntot) STORE_T64(nxt);
        __syncthreads();  // also protects the LDS alias before epilogue
    }

#pragma unroll
    for (int mt = 0; mt < 2; ++mt)
#pragma unroll
        for (int nt = 0; nt < 2; ++nt)
#pragma unroll
            for (int rg = 0; rg < 4; ++rg)
                ct[wm + mt * 16 + quad * 4 + rg][wn + nt * 16 + l16] = acc[mt][nt][rg];
    __syncthreads();

    int r = tid >> 2, c0 = (tid & 3) * 16;
    int grow = bm + r, gcol = bn + c0;
    if (grow < M) {
        float v[16];
#pragma unroll
        for (int j = 0; j < 16; ++j) v[j] = ct[r][c0 + j];
        if (Dadd) {
            const uint4* dp = (const uint4*)(Dadd + (size_t)grow * N + gcol);
            float dv[8];
            unpack8(dp[0], dv);
#pragma unroll
            for (int j = 0; j < 8; ++j) v[j] += dv[j];
            unpack8(dp[1], dv);
#pragma unroll
            for (int j = 0; j < 8; ++j) v[8 + j] += dv[j];
        }
        if (bias) {
            const uint4* bp = (const uint4*)(bias + gcol);
            float bb[8];
            unpack8(bp[0], bb);
#pragma unroll
            for (int j = 0; j < 8; ++j) v[j] += bb[j];
            unpack8(bp[1], bb);
#pragma unroll
            for (int j = 0; j < 8; ++j) v[8 + j] += bb[j];
        }
        if (do_relu)
#pragma unroll
            for (int j = 0; j < 16; ++j) v[j] = fmaxf(v[j], 0.f);
        uint uo[8];
#pragma unroll
        for (int j = 0; j < 8; ++j)
            uo[j] = (uint)f2b(v[2 * j]) | ((uint)f2b(v[2 * j + 1]) << 16);
        ushort* cp = C + (size_t)grow * N + gcol;
        *(uint4*)cp = make_uint4(uo[0], uo[1], uo[2], uo[3]);
        *(uint4*)(cp + 8) = make_uint4(uo[4], uo[5], uo[6], uo[7]);
    }
}

// ---------------------------------------------------------------------------
// thin row GEMMs (attention logits): Y[i,0..4) = X[i,:256]@W[256,4], fp32 out
// ---------------------------------------------------------------------------
__device__ inline void rowdot4_body(const ushort* __restrict__ X, const float* __restrict__ W,
                                    float* __restrict__ Y, int row) {
    int lane = threadIdx.x & 63;
    uint2 xu = *(const uint2*)(X + (size_t)row * HIDF + lane * 4);
    float x[4] = {bf_lo(xu.x), bf_hi(xu.x), bf_lo(xu.y), bf_hi(xu.y)};
    float p0 = 0.f, p1 = 0.f, p2 = 0.f, p3 = 0.f;
#pragma unroll
    for (int i = 0; i < 4; ++i) {
        int k = lane * 4 + i;
        p0 += x[i] * W[k * 4 + 0];
        p1 += x[i] * W[k * 4 + 1];
        p2 += x[i] * W[k * 4 + 2];
        p3 += x[i] * W[k * 4 + 3];
    }
#pragma unroll
    for (int off = 32; off >= 1; off >>= 1) {
        p0 += __shfl_down(p0, off, 64);
        p1 += __shfl_down(p1, off, 64);
        p2 += __shfl_down(p2, off, 64);
        p3 += __shfl_down(p3, off, 64);
    }
    if (lane == 0) {
        Y[(size_t)row * 4 + 0] = p0;
        Y[(size_t)row * 4 + 1] = p1;
        Y[(size_t)row * 4 + 2] = p2;
        Y[(size_t)row * 4 + 3] = p3;
    }
}

__global__ __launch_bounds__(256) void rowdot_tri(const ushort* XA, const float* WA, float* YA, int MA,
                                                  const ushort* XB, const float* WB, float* YB, int MB,
                                                  const ushort* XC, const float* WC, float* YC, int MC) {
    int nA = (MA + 3) / 4, nB = (MB + 3) / 4;
    int wv = threadIdx.x >> 6;
    int b = blockIdx.x;
    if (b < nA) {
        int row = b * 4 + wv;
        if (row < MA) rowdot4_body(XA, WA, YA, row);
    } else if (b < nA + nB) {
        int row = (b - nA) * 4 + wv;
        if (row < MB) rowdot4_body(XB, WB, YB, row);
    } else {
        int row = (b - nA - nB) * 4 + wv;
        if (row < MC) rowdot4_body(XC, WC, YC, row);
    }
}

__global__ __launch_bounds__(256) void rowdot_one(const ushort* XA, const float* WA, float* YA, int MA) {
    int wv = threadIdx.x >> 6;
    int row = blockIdx.x * 4 + wv;
    if (row < MA) rowdot4_body(XA, WA, YA, row);
}

// final decoder row GEMM: out[i,0..2) = X[i,:256]@W2[256,2] + b2; out dtype per flag
__global__ __launch_bounds__(256) void rowdot_out(const ushort* __restrict__ X, const ushort* __restrict__ W2,
                                                  const ushort* __restrict__ b2, void* __restrict__ Y, int M,
                                                  const int* __restrict__ flag) {
    int wv = threadIdx.x >> 6, lane = threadIdx.x & 63;
    int row = blockIdx.x * 4 + wv;
    if (row >= M) return;
    uint2 xu = *(const uint2*)(X + (size_t)row * HIDF + lane * 4);
    float x[4] = {bf_lo(xu.x), bf_hi(xu.x), bf_lo(xu.y), bf_hi(xu.y)};
    float p0 = 0.f, p1 = 0.f;
#pragma unroll
    for (int i = 0; i < 4; ++i) {
        int k = lane * 4 + i;
        p0 += x[i] * ldb(W2 + k * 2 + 0);
        p1 += x[i] * ldb(W2 + k * 2 + 1);
    }
#pragma unroll
    for (int off = 32; off >= 1; off >>= 1) {
        p0 += __shfl_down(p0, off, 64);
        p1 += __shfl_down(p1, off, 64);
    }
    if (lane == 0) {
        float v0 = p0 + ldb(b2 + 0);
        float v1 = p1 + ldb(b2 + 1);
        if (*flag) {
            ((ushort*)Y)[(size_t)row * 2 + 0] = f2b(v0);
            ((ushort*)Y)[(size_t)row * 2 + 1] = f2b(v1);
        } else {
            ((float*)Y)[(size_t)row * 2 + 0] = v0;
            ((float*)Y)[(size_t)row * 2 + 1] = v1;
        }
    }
}

// ---------------------------------------------------------------------------
// edge pass A: a = exp(leakyrelu(el[src]+er[dst](+c*e2p))); denom[dst] += a
// ---------------------------------------------------------------------------
__global__ void edge_pass_a(const int* __restrict__ src, const int* __restrict__ dst,
                            const float* __restrict__ el, const float* __restrict__ er,
                            const ushort* __restrict__ e2p, const float* __restrict__ c1,
                            float4* __restrict__ abufv, float* __restrict__ denom, int E) {
    int e = blockIdx.x * 256 + threadIdx.x;
    if (e >= E) return;
    int s = src[e], d = dst[e];
    float ev = e2p ? ldb(e2p + e) : 0.f;
    float a[NHEAD];
#pragma unroll
    for (int h = 0; h < NHEAD; ++h) {
        float v = el[s * NHEAD + h] + er[d * NHEAD + h];
        if (e2p) v += c1[h] * ev;
        v = v > 0.f ? v : 0.2f * v;  // leaky relu
        a[h] = __expf(v);
        atomicAdd(&denom[d * NHEAD + h], a[h]);
    }
    abufv[e] = make_float4(a[0], a[1], a[2], a[3]);
}

// ---------------------------------------------------------------------------
// combined graph sort (both convs, runs once): hist -> scan -> scatter(int2)
// ---------------------------------------------------------------------------
__global__ void hist2_kernel(const int* __restrict__ dst1, const int* __restrict__ dst2,
                             int* __restrict__ cnt, int E) {
    int e = blockIdx.x * 256 + threadIdx.x;
    if (e >= E) return;
    atomicAdd(&cnt[dst1[e]], 1);
    atomicAdd(&cnt[NPP + dst2[e]], 1);
}

__global__ __launch_bounds__(1024) void scan_block(const int* __restrict__ cnt, int* __restrict__ starts,
                                                   int* __restrict__ bsum, int n) {
    __shared__ int sd[1024];
    int t = threadIdx.x, i = blockIdx.x * 1024 + t;
    int x = (i < n) ? cnt[i] : 0;
    sd[t] = x;
    __syncthreads();
    for (int o = 1; o < 1024; o <<= 1) {
        int v = (t >= o) ? sd[t - o] : 0;
        __syncthreads();
        sd[t] += v;
        __syncthreads();
    }
    if (i < n) starts[i] = sd[t] - x;  // exclusive
    if (t == 1023) bsum[blockIdx.x] = sd[t];
}

__global__ __launch_bounds__(1024) void scan_small(int* __restrict__ bsum, int nb) {
    __shared__ int sd[1024];
    int t = threadIdx.x;
    int x = (t < nb) ? bsum[t] : 0;
    sd[t] = x;
    __syncthreads();
    for (int o = 1; o < 1024; o <<= 1) {
        int v = (t >= o) ? sd[t - o] : 0;
        __syncthreads();
        sd[t] += v;
        __syncthreads();
    }
    if (t < nb) bsum[t] = sd[t] - x;  // exclusive
}

__global__ __launch_bounds__(1024) void scan_add(int* __restrict__ starts, const int* __restrict__ bsum, int n) {
    int i = blockIdx.x * 1024 + threadIdx.x;
    if (i < n) starts[i] += bsum[blockIdx.x];
}

__global__ void scatter2_kernel(const int* __restrict__ src1, const int* __restrict__ dst1,
                                const int* __restrict__ src2, const int* __restrict__ dst2,
                                const int* __restrict__ starts, int* __restrict__ fill,
                                int2* __restrict__ seg, int E) {
    int e = blockIdx.x * 256 + threadIdx.x;
    if (e >= E) return;
    int d = dst1[e];
    int p = starts[d] + atomicAdd(&fill[d], 1);
    seg[p] = make_int2(src1[e], e);
    int d2 = NPP + dst2[e];
    int p2 = starts[d2] + atomicAdd(&fill[d2], 1);
    seg[p2] = make_int2(src2[e], e);
}

// ---------------------------------------------------------------------------
// gather v4: WAVE per dst, 2-wide edge unroll.
// ---------------------------------------------------------------------------
#define FMA16(al, z0, z1)                                   \
    {                                                       \
        acc[0] += (al)*bf_lo((z0).x);  acc[1] += (al)*bf_hi((z0).x);  \
        acc[2] += (al)*bf_lo((z0).y);  acc[3] += (al)*bf_hi((z0).y);  \
        acc[4] += (al)*bf_lo((z0).z);  acc[5] += (al)*bf_hi((z0).z);  \
        acc[6] += (al)*bf_lo((z0).w);  acc[7] += (al)*bf_hi((z0).w);  \
        acc[8] += (al)*bf_lo((z1).x);  acc[9] += (al)*bf_hi((z1).x);  \
        acc[10] += (al)*bf_lo((z1).y); acc[11] += (al)*bf_hi((z1).y); \
        acc[12] += (al)*bf_lo((z1).z); acc[13] += (al)*bf_hi((z1).z); \
        acc[14] += (al)*bf_lo((z1).w); acc[15] += (al)*bf_hi((z1).w); \
    }

__global__ __launch_bounds__(256) void gather_agg(const int2* __restrict__ seg, const int* __restrict__ starts,
                                                  const float4* __restrict__ abufv, const float4* __restrict__ denomv,
                                                  const ushort* __restrict__ zs, ushort* __restrict__ aggb,
                                                  int r0, int r1, int first) {
    int wave = threadIdx.x >> 6, lane = threadIdx.x & 63;
    int d = blockIdx.x * 4 + wave;
    int h = lane >> 4;            // head this lane accumulates
    int c16 = (lane & 15) * 16;   // col base within [0,256)
    int s0 = starts[d], s1 = starts[d + 1];
    float4 dn = denomv[d];
    float rd = 0.25f / fmaxf(h == 0 ? dn.x : h == 1 ? dn.y : h == 2 ? dn.z : dn.w, 1e-9f);
    float acc[16];
#pragma unroll
    for (int j = 0; j < 16; ++j) acc[j] = 0.f;

    const size_t zoff = (size_t)h * 256 + c16;
    int i = s0;
    for (; i + 1 < s1; i += 2) {
        int2 e0 = seg[i], e1 = seg[i + 1];
        bool v0 = (e0.x >= r0) && (e0.x < r1);
        bool v1 = (e1.x >= r0) && (e1.x < r1);
        float4 a0, a1;
        uint4 p00, p01, p10, p11;
        if (v0) {
            a0 = abufv[e0.y];
            const ushort* zr = zs + (size_t)(e0.x - r0) * HD4 + zoff;
            p00 = *(const uint4*)zr;
            p01 = *(const uint4*)(zr + 8);
        }
        if (v1) {
            a1 = abufv[e1.y];
            const ushort* zr = zs + (size_t)(e1.x - r0) * HD4 + zoff;
            p10 = *(const uint4*)zr;
            p11 = *(const uint4*)(zr + 8);
        }
        if (v0) {
            float al = (h == 0 ? a0.x : h == 1 ? a0.y : h == 2 ? a0.z : a0.w) * rd;
            FMA16(al, p00, p01);
        }
        if (v1) {
            float al = (h == 0 ? a1.x : h == 1 ? a1.y : h == 2 ? a1.z : a1.w) * rd;
            FMA16(al, p10, p11);
        }
    }
    if (i < s1) {
        int2 e0 = seg[i];
        if (e0.x >= r0 && e0.x < r1) {
            float4 a0 = abufv[e0.y];
            const ushort* zr = zs + (size_t)(e0.x - r0) * HD4 + zoff;
            uint4 p00 = *(const uint4*)zr;
            uint4 p01 = *(const uint4*)(zr + 8);
            float al = (h == 0 ? a0.x : h == 1 ? a0.y : h == 2 ? a0.z : a0.w) * rd;
            FMA16(al, p00, p01);
        }
    }

#pragma unroll
    for (int j = 0; j < 16; ++j) {
        acc[j] += __shfl_xor(acc[j], 16, 64);
        acc[j] += __shfl_xor(acc[j], 32, 64);
    }

    if (h == 0) {
        size_t oi = (size_t)d * HIDF + c16;
        if (!first) {
            uint4 p0 = *(const uint4*)(aggb + oi);
            uint4 p1 = *(const uint4*)(aggb + oi + 8);
            acc[0] += bf_lo(p0.x);  acc[1] += bf_hi(p0.x);
            acc[2] += bf_lo(p0.y);  acc[3] += bf_hi(p0.y);
            acc[4] += bf_lo(p0.z);  acc[5] += bf_hi(p0.z);
            acc[6] += bf_lo(p0.w);  acc[7] += bf_hi(p0.w);
            acc[8] += bf_lo(p1.x);  acc[9] += bf_hi(p1.x);
            acc[10] += bf_lo(p1.y); acc[11] += bf_hi(p1.y);
            acc[12] += bf_lo(p1.z); acc[13] += bf_hi(p1.z);
            acc[14] += bf_lo(p1.w); acc[15] += bf_hi(p1.w);
        }
        uint uo[8];
#pragma unroll
        for (int j = 0; j < 8; ++j)
            uo[j] = (uint)f2b(acc[2 * j]) | ((uint)f2b(acc[2 * j + 1]) << 16);
        *(uint4*)(aggb + oi) = make_uint4(uo[0], uo[1], uo[2], uo[3]);
        *(uint4*)(aggb + oi + 8) = make_uint4(uo[4], uo[5], uo[6], uo[7]);
    }
}

// ---------------------------------------------------------------------------
extern "C" void kernel_launch(void* const* d_in, const int* in_sizes, int n_in,
                              void* d_out, int out_size, void* d_ws, size_t ws_size,
                              hipStream_t stream) {
    const int* src1 = (const int*)d_in[26];
    const int* dst1 = (const int*)d_in[27];
    const int* src2 = (const int*)d_in[28];
    const int* dst2 = (const int*)d_in[29];

    static const int csz[N_CVT] = {
        N_LINK * 8, N_FLOW * 16, N_PATH * 8, NEDGE,
        8 * 256, 256, 16 * 256, 256, 8 * 256, 256,
        256 * 1024, 256 * 1024, 1024, 1024, 1024, 1024,
        256 * 256, 256 * 1024, 256 * 1024, 1024, 1024, 256 * 256,
        768 * 256, 256, 256 * 2, 2};

    // ---- workspace layout (bytes, 256B-aligned slots) ----
    char* base = (char*)d_ws;
    size_t off = 0;
    auto alloc = [&](size_t bytes) { size_t r = off; off += (bytes + 255) & ~255ull; return r; };

    size_t o_flag = alloc(256);
    CvtArgs ca;
    int coff[N_CVT];
    {
        int acc = 0;
        for (int i = 0; i < N_CVT; ++i) {
            ca.src[i] = d_in[i];
            ca.sz[i] = csz[i];
            ca.off[i] = acc;
            coff[i] = acc;
            acc += (csz[i] + 127) & ~127;
        }
        alloc((size_t)acc * 2);
    }
    const ushort* cvt = (const ushort*)(base + o_flag + 256);
    auto IN = [&](int i) { return cvt + coff[i]; };

    size_t o_h_link  = alloc((size_t)N_LINK * HIDF * 2);
    size_t o_h_flow  = alloc((size_t)N_FLOW * HIDF * 2);
    size_t o_h_path0 = alloc((size_t)N_PATH * HIDF * 2);  // reused as 'hidden'
    size_t o_h1      = alloc((size_t)N_PATH * HIDF * 2);
    size_t o_h2      = alloc((size_t)N_PATH * HIDF * 2);
    size_t o_aggb    = alloc((size_t)N_PATH * HIDF * 2);  // bf16 gather target
    size_t o_el      = alloc((size_t)N_LINK * NHEAD * 4);
    size_t o_el2     = alloc((size_t)N_FLOW * NHEAD * 4);
    size_t o_er      = alloc((size_t)N_PATH * NHEAD * 4);
    size_t o_abuf    = alloc((size_t)NEDGE * NHEAD * 4);
    // contiguous zero-region: denom1 + denom2 + cnt + fill (one memset)
    size_t o_denom1  = alloc((size_t)N_PATH * NHEAD * 4);
    size_t o_denom2  = alloc((size_t)N_PATH * NHEAD * 4);
    size_t o_cnt     = alloc((size_t)NSCAN * 4);
    size_t o_fill    = alloc((size_t)NSCAN * 4);
    size_t zero_span = o_fill + (size_t)NSCAN * 4 - o_denom1;
    size_t o_wl1 = alloc(HIDF * NHEAD * 4);
    size_t o_wr1 = alloc(HIDF * NHEAD * 4);
    size_t o_wl2 = alloc(HIDF * NHEAD * 4);
    size_t o_wr2 = alloc(HIDF * NHEAD * 4);
    size_t o_c1  = alloc(NHEAD * 4);
    size_t o_bt_src1 = alloc((size_t)HD4 * HIDF * 2);
    size_t o_bt_src2 = alloc((size_t)HD4 * HIDF * 2);
    size_t o_bt_rw1  = alloc((size_t)HIDF * HIDF * 2);
    size_t o_bt_rw2  = alloc((size_t)HIDF * HIDF * 2);
    size_t o_bt_w1ac = alloc((size_t)HIDF * HIDF * 2);
    size_t o_bt_w1b  = alloc((size_t)HIDF * HIDF * 2);
    size_t o_starts = alloc((size_t)(NSCAN + 1) * 4);
    size_t o_seg    = alloc((size_t)(2 * NEDGE) * 8);
    size_t o_bsum   = alloc(1024 * 4);
    size_t o_zs = off;  // adaptive chunk buffer takes the rest

    int* flag = (int*)(base + o_flag);

    long avail = (long)ws_size - (long)off;
    long Rl = avail / (HD4 * 2);
    int R = (int)(Rl > N_FLOW ? N_FLOW : Rl);
    R &= ~63;
    if (R > RCAP) R = RCAP;  // keep zs chunk L3-hot between gemm write and gather read
    detect_dtype<<<1, 64, 0, stream>>>((const ushort*)d_in[13], flag);
    if (R < 256) {
        sentinel_fill<<<(out_size + 255) / 256, 256, 0, stream>>>(d_out, out_size,
                                                                  (float)(ws_size >> 20), flag);
        return;
    }

    ushort* h_link = (ushort*)(base + o_h_link);
    ushort* h_flow = (ushort*)(base + o_h_flow);
    ushort* h_path0 = (ushort*)(base + o_h_path0);
    ushort* h1 = (ushort*)(base + o_h1);
    ushort* h2 = (ushort*)(base + o_h2);
    ushort* zs = (ushort*)(base + o_zs);
    ushort* aggb = (ushort*)(base + o_aggb);
    float* el = (float*)(base + o_el);
    float* el2 = (float*)(base + o_el2);
    float* er = (float*)(base + o_er);
    float* abuf = (float*)(base + o_abuf);
    float* denom1 = (float*)(base + o_denom1);
    float* denom2 = (float*)(base + o_denom2);
    int* cnt = (int*)(base + o_cnt);
    int* fill = (int*)(base + o_fill);
    float* wl1 = (float*)(base + o_wl1);
    float* wr1 = (float*)(base + o_wr1);
    float* wl2 = (float*)(base + o_wl2);
    float* wr2 = (float*)(base + o_wr2);
    float* c1 = (float*)(base + o_c1);
    ushort* bt_src1 = (ushort*)(base + o_bt_src1);
    ushort* bt_src2 = (ushort*)(base + o_bt_src2);
    ushort* bt_rw1 = (ushort*)(base + o_bt_rw1);
    ushort* bt_rw2 = (ushort*)(base + o_bt_rw2);
    ushort* bt_w1ac = (ushort*)(base + o_bt_w1ac);
    ushort* bt_w1b = (ushort*)(base + o_bt_w1b);
    int* starts = (int*)(base + o_starts);
    int2* seg = (int2*)(base + o_seg);
    int* bsum = (int*)(base + o_bsum);

    const int EB = (NEDGE + 255) / 256;

    // ---- zero denoms + cnt + fill; graph sort (depends only on edge lists) ----
    hipMemsetAsync(denom1, 0, zero_span, stream);
    hist2_kernel<<<EB, 256, 0, stream>>>(dst1, dst2, cnt, NEDGE);
    scan_block<<<NB2, 1024, 0, stream>>>(cnt, starts, bsum, NSCAN);
    scan_small<<<1, 1024, 0, stream>>>(bsum, NB2);
    scan_add<<<NB2, 1024, 0, stream>>>(starts, bsum, NSCAN);
    scatter2_kernel<<<EB, 256, 0, stream>>>(src1, dst1, src2, dst2, starts, fill, seg, NEDGE);

    // ---- convert inputs + prep ----
    convert_inputs<<<dim3((N_FLOW * 16 + 255) / 256, N_CVT), 256, 0, stream>>>(
        ca, (ushort*)(base + o_flag + 256), flag);
    PrepArgs pa;
    pa.fc[0] = IN(10); pa.at[0] = IN(13); pa.out[0] = wl1;
    pa.fc[1] = IN(11); pa.at[1] = IN(14); pa.out[1] = wr1;
    pa.fc[2] = IN(17); pa.at[2] = IN(19); pa.out[2] = wl2;
    pa.fc[3] = IN(18); pa.at[3] = IN(20); pa.out[3] = wr2;
    pa.fc[4] = IN(12); pa.at[4] = IN(15); pa.out[4] = c1;
    prep_fold<<<1025, 256, 0, stream>>>(pa);
    TJobs tj;
    tj.s1[0] = IN(10); tj.s2[0] = nullptr;            tj.d[0] = bt_src1; tj.K[0] = HIDF; tj.N[0] = HD4;
    tj.s1[1] = IN(17); tj.s2[1] = nullptr;            tj.d[1] = bt_src2; tj.K[1] = HIDF; tj.N[1] = HD4;
    tj.s1[2] = IN(16); tj.s2[2] = nullptr;            tj.d[2] = bt_rw1;  tj.K[2] = HIDF; tj.N[2] = HIDF;
    tj.s1[3] = IN(21); tj.s2[3] = nullptr;            tj.d[3] = bt_rw2;  tj.K[3] = HIDF; tj.N[3] = HIDF;
    tj.s1[4] = IN(22); tj.s2[4] = IN(22) + 512 * 256; tj.d[4] = bt_w1ac; tj.K[4] = HIDF; tj.N[4] = HIDF;
    tj.s1[5] = IN(22) + 256 * 256; tj.s2[5] = nullptr; tj.d[5] = bt_w1b; tj.K[5] = HIDF; tj.N[5] = HIDF;
    transpose_batch<<<dim3(256, 6), 256, 0, stream>>>(tj);

    proj_all<<<N_LINK / 8 + N_FLOW / 8 + N_PATH / 8, 256, 0, stream>>>(
        IN(0), IN(4), IN(5), h_link, IN(1), IN(6), IN(7), h_flow, IN(2), IN(8), IN(9), h_path0);

    ushort* hidden = h_path0;  // reuse after conv1

    // conv1-el, conv1-er, conv2-el all depend only on proj outputs
    rowdot_tri<<<(N_LINK + 3) / 4 + (N_PATH + 3) / 4 + (N_FLOW + 3) / 4, 256, 0, stream>>>(
        h_link, wl1, el, N_LINK, h_path0, wr1, er, N_PATH, h_flow, wl2, el2, N_FLOW);

    // ================= conv1: link -> path =================
    edge_pass_a<<<EB, 256, 0, stream>>>(src1, dst1, el, er, IN(3), c1, (float4*)abuf, denom1, NEDGE);
    for (int r0 = 0; r0 < N_LINK; r0 += R) {
        int r1 = r0 + R < N_LINK ? r0 + R : N_LINK;
        gemm_mfma<<<dim3(HD4 / GTN, (r1 - r0 + GTM - 1) / GTM), 256, 0, stream>>>(
            h_link + (size_t)r0 * HIDF, bt_src1, HIDF, nullptr, nullptr, 0,
            nullptr, nullptr, 0, zs, r1 - r0, HD4);
        gather_agg<<<N_PATH / 4, 256, 0, stream>>>(seg, starts, (const float4*)abuf, (const float4*)denom1,
                                                   zs, aggb, r0, r1, r0 == 0);
    }
    gemm_mfma64<<<dim3(HIDF / 64, (N_PATH + 63) / 64), 256, 0, stream>>>(
        h_path0, bt_rw1, HIDF, nullptr, nullptr, 0, aggb, nullptr, 1, h1, N_PATH, HIDF);

    // ================= conv2: flow -> path (zs chunks kept L3-hot) =================
    rowdot_one<<<(N_PATH + 3) / 4, 256, 0, stream>>>(h1, wr2, er, N_PATH);
    edge_pass_a<<<EB, 256, 0, stream>>>(src2, dst2, el2, er, nullptr, nullptr, (float4*)abuf, denom2, NEDGE);
    for (int r0 = 0; r0 < N_FLOW; r0 += R) {
        int r1 = r0 + R < N_FLOW ? r0 + R : N_FLOW;
        gemm_mfma<<<dim3(HD4 / GTN, (r1 - r0 + GTM - 1) / GTM), 256, 0, stream>>>(
            h_flow + (size_t)r0 * HIDF, bt_src2, HIDF, nullptr, nullptr, 0,
            nullptr, nullptr, 0, zs, r1 - r0, HD4);
        gather_agg<<<N_PATH / 4, 256, 0, stream>>>(seg, starts + NPP, (const float4*)abuf, (const float4*)denom2,
                                                   zs, aggb, r0, r1, r0 == 0);
    }
    gemm_mfma64<<<dim3(HIDF / 64, (N_PATH + 63) / 64), 256, 0, stream>>>(
        h1, bt_rw2, HIDF, nullptr, nullptr, 0, aggb, nullptr, 1, h2, N_PATH, HIDF);

    // ---- decoder ----
    gemm_mfma64<<<dim3(HIDF / 64, (N_PATH + 63) / 64), 256, 0, stream>>>(
        h2, bt_w1ac, HIDF, h1, bt_w1b, HIDF, nullptr, IN(23), 1, hidden, N_PATH, HIDF);
    rowdot_out<<<(N_PATH + 3) / 4, 256, 0, stream>>>(hidden, IN(24), IN(25), d_out, N_PATH, flag);
}

// Round 16
// 552.767 us; speedup vs baseline: 1.0769x; 1.0769x over previous
//
#include <hip/hip_runtime.h>
#include <math.h>

typedef unsigned int uint;
typedef unsigned short ushort;

#define HIDF 256
#define HD4 1024
#define NHEAD 4
#define N_LINK 2000
#define N_FLOW 30000
#define N_PATH 50000
#define NEDGE 120000
#define N_CVT 26
#define NPP (N_PATH + 1)
#define NSCAN (2 * NPP)
#define NB2 ((NSCAN + 1023) / 1024)  // 98

// ---- bf16 helpers (bf16 = high 16 bits of fp32) ----
__device__ inline float bf_lo(uint u) { return __uint_as_float(u << 16); }
__device__ inline float bf_hi(uint u) { return __uint_as_float(u & 0xffff0000u); }
__device__ inline float ldb(const ushort* p) { return __uint_as_float(((uint)*p) << 16); }
__device__ inline ushort f2b(float f) {  // round-to-nearest-even
    uint x = __float_as_uint(f);
    return (ushort)((x + 0x7fffu + ((x >> 16) & 1u)) >> 16);
}
__device__ inline void unpack8(uint4 v, float* f) {
    f[0] = bf_lo(v.x); f[1] = bf_hi(v.x);
    f[2] = bf_lo(v.y); f[3] = bf_hi(v.y);
    f[4] = bf_lo(v.z); f[5] = bf_hi(v.z);
    f[6] = bf_lo(v.w); f[7] = bf_hi(v.w);
}

typedef __attribute__((ext_vector_type(8))) short bf16x8;
typedef __attribute__((ext_vector_type(4))) float f32x4;

// ---------------------------------------------------------------------------
// dtype detect: probe even-index ushorts of attn_l1. flag: 1 = bf16, 0 = fp32.
// ---------------------------------------------------------------------------
__global__ void detect_dtype(const ushort* __restrict__ probe, int* __restrict__ flag) {
    int lane = threadIdx.x;  // 0..63
    uint u = probe[lane * 2];
    int e = (u >> 7) & 0xFF;
    bool sane = (u != 0u) && (e <= 0x4F);
    unsigned long long m = __ballot(sane);
    if (lane == 0) *flag = (__popcll(m) >= 48) ? 1 : 0;
}

// ---------------------------------------------------------------------------
// batched input conversion into bf16 arena (passthrough when already bf16)
// ---------------------------------------------------------------------------
struct CvtArgs {
    const void* src[N_CVT];
    int off[N_CVT];
    int sz[N_CVT];
};

__global__ __launch_bounds__(256) void convert_inputs(CvtArgs a, ushort* __restrict__ dst,
                                                      const int* __restrict__ flag) {
    int i = blockIdx.y;
    int idx = blockIdx.x * 256 + threadIdx.x;
    if (idx >= a.sz[i]) return;
    ushort v;
    if (*flag) v = ((const ushort*)a.src[i])[idx];
    else       v = f2b(((const float*)a.src[i])[idx]);
    dst[a.off[i] + idx] = v;
}

// sentinel: broadcast ws_MB so a too-small workspace reveals its size
__global__ void sentinel_fill(void* out, int n, float val, const int* flag) {
    int i = blockIdx.x * 256 + threadIdx.x;
    if (i >= n) return;
    if (*flag) ((ushort*)out)[i] = f2b(val);
    else       ((float*)out)[i] = val;
}

// ---------------------------------------------------------------------------
// prep_fold: one WAVE per output scalar (4100 waves).
// ---------------------------------------------------------------------------
struct PrepArgs {
    const ushort* fc[5];
    const ushort* at[5];
    float* out[5];
};

__global__ __launch_bounds__(256) void prep_fold(PrepArgs pa) {
    int w = blockIdx.x * 4 + (threadIdx.x >> 6);
    int lane = threadIdx.x & 63;
    int m, k, h;
    if (w < 4096) {
        m = w >> 10;
        k = (w >> 2) & 255;
        h = w & 3;
    } else if (w < 4100) {
        m = 4;
        k = 0;
        h = w - 4096;
    } else {
        return;
    }
    size_t fbase = (m == 4) ? 0 : (size_t)k * HD4;
    uint2 fv = *(const uint2*)(pa.fc[m] + fbase + h * HIDF + lane * 4);
    uint2 av = *(const uint2*)(pa.at[m] + h * HIDF + lane * 4);
    float s = bf_lo(fv.x) * bf_lo(av.x) + bf_hi(fv.x) * bf_hi(av.x) +
              bf_lo(fv.y) * bf_lo(av.y) + bf_hi(fv.y) * bf_hi(av.y);
#pragma unroll
    for (int off = 32; off >= 1; off >>= 1) s += __shfl_down(s, off, 64);
    if (lane == 0) {
        if (m < 4) pa.out[m][k * NHEAD + h] = s;
        else       pa.out[4][h] = s;
    }
}

// ---------------------------------------------------------------------------
// batched 32x32 transpose: d[n*K+k] = s1[k*N+n] (+ s2[k*N+n] if s2)
// ---------------------------------------------------------------------------
struct TJobs {
    const ushort* s1[6];
    const ushort* s2[6];
    ushort* d[6];
    int K[6];
    int N[6];
};

__global__ __launch_bounds__(256) void transpose_batch(TJobs tj) {
    int j = blockIdx.y;
    int K = tj.K[j], N = tj.N[j];
    int tilesx = N >> 5;
    if ((int)blockIdx.x >= tilesx * (K >> 5)) return;
    int n0 = (blockIdx.x % tilesx) * 32, k0 = (blockIdx.x / tilesx) * 32;
    const ushort* s1 = tj.s1[j];
    const ushort* s2 = tj.s2[j];
    ushort* dst = tj.d[j];
    __shared__ ushort tile[32][33];
    int jj = threadIdx.x & 31, i0 = threadIdx.x >> 5;
    for (int i = i0; i < 32; i += 8) {
        size_t idx = (size_t)(k0 + i) * N + n0 + jj;
        float v = ldb(s1 + idx);
        if (s2) v += ldb(s2 + idx);
        tile[i][jj] = f2b(v);
    }
    __syncthreads();
    for (int i = i0; i < 32; i += 8) dst[(size_t)(n0 + i) * K + k0 + jj] = tile[jj][i];
}

// ---------------------------------------------------------------------------
// proj v2: 8 rows/block, 8 cols/thread, uint4 loads/stores throughout.
// ---------------------------------------------------------------------------
template <int K>
__device__ inline void proj_body(const ushort* __restrict__ X, const ushort* __restrict__ W,
                                 const ushort* __restrict__ bias, ushort* __restrict__ Y, int rowblk) {
    int t = threadIdx.x;
    int r = t >> 5;            // 0..7 row within the 8-row group
    int c8 = (t & 31) * 8;     // col base
    int i = rowblk * 8 + r;
    float x[K];
    const uint4* xp = (const uint4*)(X + (size_t)i * K);
    unpack8(xp[0], x);
    if (K == 16) unpack8(xp[1], x + 8);
    float s[8];
    unpack8(*(const uint4*)(bias + c8), s);
#pragma unroll
    for (int k = 0; k < K; ++k) {
        float w[8];
        unpack8(*(const uint4*)(W + k * HIDF + c8), w);
        float xv = x[k];
#pragma unroll
        for (int j = 0; j < 8; ++j) s[j] += xv * w[j];
    }
    uint uo[4];
#pragma unroll
    for (int j = 0; j < 4; ++j) {
        float a = fmaxf(s[2 * j], 0.f), b = fmaxf(s[2 * j + 1], 0.f);
        uo[j] = (uint)f2b(a) | ((uint)f2b(b) << 16);
    }
    *(uint4*)(Y + (size_t)i * HIDF + c8) = make_uint4(uo[0], uo[1], uo[2], uo[3]);
}

__global__ __launch_bounds__(256) void proj_all(const ushort* X0, const ushort* W0, const ushort* b0, ushort* Y0,
                                                const ushort* X1, const ushort* W1, const ushort* b1, ushort* Y1,
                                                const ushort* X2, const ushort* W2, const ushort* b2, ushort* Y2) {
    int b = blockIdx.x;
    const int BL = N_LINK / 8, BF = N_FLOW / 8;
    if (b < BL) proj_body<8>(X0, W0, b0, Y0, b);
    else if (b < BL + BF) proj_body<16>(X1, W1, b1, Y1, b - BL);
    else proj_body<8>(X2, W2, b2, Y2, b - BL - BF);
}

// ---------------------------------------------------------------------------
// MFMA bf16 GEMM v2 (round-9 config): 64x128 block, 4 waves of 64x32, BK=32,
// double-buffered LDS, ONE barrier per K-iter.  (used for the zs GEMMs)
// ---------------------------------------------------------------------------
#define GTM 64
#define GTN 128
#define GTK 32
#define GPAD 40

#define LOAD_TILE(t)                                                          \
    {                                                                         \
        const ushort* A;                                                      \
        const ushort* BT;                                                     \
        int K, k0;                                                            \
        if ((t) < nt1) { A = A1; BT = B1T; K = K1; k0 = (t)*GTK; }            \
        else           { A = A2; BT = B2T; K = K2; k0 = ((t)-nt1) * GTK; }    \
        av = (bm + ar < M) ? *(const uint4*)(A + (size_t)(bm + ar) * K + k0 + aq * 8) : z4; \
        bv0 = *(const uint4*)(BT + (size_t)(bn + ar) * K + k0 + aq * 8);      \
        bv1 = *(const uint4*)(BT + (size_t)(bn + ar + 64) * K + k0 + aq * 8); \
    }

#define STORE_TILE(b)                                                         \
    {                                                                         \
        *(uint4*)&As[b][ar][aq * 8] = av;                                     \
        *(uint4*)&Bs[b][ar][aq * 8] = bv0;                                    \
        *(uint4*)&Bs[b][ar + 64][aq * 8] = bv1;                               \
    }

__global__ __launch_bounds__(256) void gemm_mfma(const ushort* __restrict__ A1, const ushort* __restrict__ B1T, int K1,
                                                 const ushort* __restrict__ A2, const ushort* __restrict__ B2T, int K2,
                                                 const ushort* __restrict__ Dadd, const ushort* __restrict__ bias,
                                                 int do_relu, ushort* __restrict__ C, int M, int N) {
    __shared__ __align__(16) ushort As[2][GTM][GPAD];
    __shared__ __align__(16) ushort Bs[2][GTN][GPAD];

    int tid = threadIdx.x;
    int lane = tid & 63, wave = tid >> 6;
    int quad = lane >> 4, l16 = lane & 15;
    int wn = wave * 32;
    int bm = blockIdx.y * GTM, bn = blockIdx.x * GTN;

    f32x4 acc[4][2];
    f32x4 zf = {0.f, 0.f, 0.f, 0.f};
#pragma unroll
    for (int i = 0; i < 4; ++i) {
        acc[i][0] = zf;
        acc[i][1] = zf;
    }

    int ar = tid >> 2, aq = tid & 3;
    uint4 av, bv0, bv1;
    uint4 z4 = {0, 0, 0, 0};

    int nt1 = K1 / GTK;
    int ntot = nt1 + K2 / GTK;

    LOAD_TILE(0);
    STORE_TILE(0);
    __syncthreads();

    for (int t = 0; t < ntot; ++t) {
        int cur = t & 1, nxt = cur ^ 1;
        if (t + 1 < ntot) LOAD_TILE(t + 1);

        bf16x8 af[4], bf[2];
#pragma unroll
        for (int mt = 0; mt < 4; ++mt) af[mt] = *(const bf16x8*)&As[cur][mt * 16 + l16][quad * 8];
#pragma unroll
        for (int ct = 0; ct < 2; ++ct) bf[ct] = *(const bf16x8*)&Bs[cur][wn + ct * 16 + l16][quad * 8];
#pragma unroll
        for (int mt = 0; mt < 4; ++mt)
#pragma unroll
            for (int ct = 0; ct < 2; ++ct)
                acc[mt][ct] = __builtin_amdgcn_mfma_f32_16x16x32_bf16(af[mt], bf[ct], acc[mt][ct], 0, 0, 0);

        if (t + 1 < ntot) STORE_TILE(nxt);
        __syncthreads();
    }

#pragma unroll
    for (int mt = 0; mt < 4; ++mt) {
#pragma unroll
        for (int ct = 0; ct < 2; ++ct) {
            int col = bn + wn + ct * 16 + l16;
#pragma unroll
            for (int rg = 0; rg < 4; ++rg) {
                int row = bm + mt * 16 + quad * 4 + rg;
                if (row >= M) continue;
                float v = acc[mt][ct][rg];
                if (Dadd) v += ldb(Dadd + (size_t)row * N + col);
                if (bias) v += ldb(bias + col);
                if (do_relu) v = fmaxf(v, 0.f);
                C[(size_t)row * N + col] = f2b(v);
            }
        }
    }
}

// ---------------------------------------------------------------------------
// MFMA bf16 GEMM 64x64 (high-occupancy, N=256 GEMMs) with VECTORIZED epilogue
// via LDS-aliased fp32 staging tile.
// ---------------------------------------------------------------------------
#define LOAD_T64(t)                                                           \
    {                                                                         \
        const ushort* A;                                                      \
        const ushort* BT;                                                     \
        int K, k0;                                                            \
        if ((t) < nt1) { A = A1; BT = B1T; K = K1; k0 = (t)*GTK; }            \
        else           { A = A2; BT = B2T; K = K2; k0 = ((t)-nt1) * GTK; }    \
        av = (bm + ar < M) ? *(const uint4*)(A + (size_t)(bm + ar) * K + k0 + aq * 8) : z4; \
        bv = *(const uint4*)(BT + (size_t)(bn + ar) * K + k0 + aq * 8);       \
    }

#define STORE_T64(b)                                                          \
    {                                                                         \
        *(uint4*)&As[b][ar][aq * 8] = av;                                     \
        *(uint4*)&Bs[b][ar][aq * 8] = bv;                                     \
    }

__global__ __launch_bounds__(256) void gemm_mfma64(const ushort* __restrict__ A1, const ushort* __restrict__ B1T, int K1,
                                                   const ushort* __restrict__ A2, const ushort* __restrict__ B2T, int K2,
                                                   const ushort* __restrict__ Dadd, const ushort* __restrict__ bias,
                                                   int do_relu, ushort* __restrict__ C, int M, int N) {
    __shared__ __align__(16) char smem[20480];
    auto As = (ushort(*)[64][GPAD])smem;            // [2][64][40]
    auto Bs = (ushort(*)[64][GPAD])(smem + 10240);  // [2][64][40]
    auto ct = (float(*)[68])smem;                   // [64][68]

    int tid = threadIdx.x;
    int lane = tid & 63, wave = tid >> 6;
    int quad = lane >> 4, l16 = lane & 15;
    int wm = (wave >> 1) * 32, wn = (wave & 1) * 32;
    int bm = blockIdx.y * 64, bn = blockIdx.x * 64;

    f32x4 acc[2][2];
    f32x4 zf = {0.f, 0.f, 0.f, 0.f};
    acc[0][0] = zf; acc[0][1] = zf; acc[1][0] = zf; acc[1][1] = zf;

    int ar = tid >> 2, aq = tid & 3;
    uint4 av, bv;
    uint4 z4 = {0, 0, 0, 0};

    int nt1 = K1 / GTK;
    int ntot = nt1 + K2 / GTK;

    LOAD_T64(0);
    STORE_T64(0);
    __syncthreads();

    for (int t = 0; t < ntot; ++t) {
        int cur = t & 1, nxt = cur ^ 1;
        if (t + 1 < ntot) LOAD_T64(t + 1);

        bf16x8 af[2], bf[2];
#pragma unroll
        for (int mt = 0; mt < 2; ++mt) af[mt] = *(const bf16x8*)&As[cur][wm + mt * 16 + l16][quad * 8];
#pragma unroll
        for (int nt = 0; nt < 2; ++nt) bf[nt] = *(const bf16x8*)&Bs[cur][wn + nt * 16 + l16][quad * 8];
#pragma unroll
        for (int mt = 0; mt < 2; ++mt)
#pragma unroll
            for (int nt = 0; nt < 2; ++nt)
                acc[mt][nt] = __builtin_amdgcn_mfma_f32_16x16x32_bf16(af[mt], bf[nt], acc[mt][nt], 0, 0, 0);

        if (t + 1 < ntot) STORE_T64(nxt);
        __syncthreads();  // also protects the LDS alias before epilogue
    }

#pragma unroll
    for (int mt = 0; mt < 2; ++mt)
#pragma unroll
        for (int nt = 0; nt < 2; ++nt)
#pragma unroll
            for (int rg = 0; rg < 4; ++rg)
                ct[wm + mt * 16 + quad * 4 + rg][wn + nt * 16 + l16] = acc[mt][nt][rg];
    __syncthreads();

    int r = tid >> 2, c0 = (tid & 3) * 16;
    int grow = bm + r, gcol = bn + c0;
    if (grow < M) {
        float v[16];
#pragma unroll
        for (int j = 0; j < 16; ++j) v[j] = ct[r][c0 + j];
        if (Dadd) {
            const uint4* dp = (const uint4*)(Dadd + (size_t)grow * N + gcol);
            float dv[8];
            unpack8(dp[0], dv);
#pragma unroll
            for (int j = 0; j < 8; ++j) v[j] += dv[j];
            unpack8(dp[1], dv);
#pragma unroll
            for (int j = 0; j < 8; ++j) v[8 + j] += dv[j];
        }
        if (bias) {
            const uint4* bp = (const uint4*)(bias + gcol);
            float bb[8];
            unpack8(bp[0], bb);
#pragma unroll
            for (int j = 0; j < 8; ++j) v[j] += bb[j];
            unpack8(bp[1], bb);
#pragma unroll
            for (int j = 0; j < 8; ++j) v[8 + j] += bb[j];
        }
        if (do_relu)
#pragma unroll
            for (int j = 0; j < 16; ++j) v[j] = fmaxf(v[j], 0.f);
        uint uo[8];
#pragma unroll
        for (int j = 0; j < 8; ++j)
            uo[j] = (uint)f2b(v[2 * j]) | ((uint)f2b(v[2 * j + 1]) << 16);
        ushort* cp = C + (size_t)grow * N + gcol;
        *(uint4*)cp = make_uint4(uo[0], uo[1], uo[2], uo[3]);
        *(uint4*)(cp + 8) = make_uint4(uo[4], uo[5], uo[6], uo[7]);
    }
}

// ---------------------------------------------------------------------------
// thin row GEMMs (attention logits): Y[i,0..4) = X[i,:256]@W[256,4], fp32 out
// ---------------------------------------------------------------------------
__device__ inline void rowdot4_body(const ushort* __restrict__ X, const float* __restrict__ W,
                                    float* __restrict__ Y, int row) {
    int lane = threadIdx.x & 63;
    uint2 xu = *(const uint2*)(X + (size_t)row * HIDF + lane * 4);
    float x[4] = {bf_lo(xu.x), bf_hi(xu.x), bf_lo(xu.y), bf_hi(xu.y)};
    float p0 = 0.f, p1 = 0.f, p2 = 0.f, p3 = 0.f;
#pragma unroll
    for (int i = 0; i < 4; ++i) {
        int k = lane * 4 + i;
        p0 += x[i] * W[k * 4 + 0];
        p1 += x[i] * W[k * 4 + 1];
        p2 += x[i] * W[k * 4 + 2];
        p3 += x[i] * W[k * 4 + 3];
    }
#pragma unroll
    for (int off = 32; off >= 1; off >>= 1) {
        p0 += __shfl_down(p0, off, 64);
        p1 += __shfl_down(p1, off, 64);
        p2 += __shfl_down(p2, off, 64);
        p3 += __shfl_down(p3, off, 64);
    }
    if (lane == 0) {
        Y[(size_t)row * 4 + 0] = p0;
        Y[(size_t)row * 4 + 1] = p1;
        Y[(size_t)row * 4 + 2] = p2;
        Y[(size_t)row * 4 + 3] = p3;
    }
}

__global__ __launch_bounds__(256) void rowdot_tri(const ushort* XA, const float* WA, float* YA, int MA,
                                                  const ushort* XB, const float* WB, float* YB, int MB,
                                                  const ushort* XC, const float* WC, float* YC, int MC) {
    int nA = (MA + 3) / 4, nB = (MB + 3) / 4;
    int wv = threadIdx.x >> 6;
    int b = blockIdx.x;
    if (b < nA) {
        int row = b * 4 + wv;
        if (row < MA) rowdot4_body(XA, WA, YA, row);
    } else if (b < nA + nB) {
        int row = (b - nA) * 4 + wv;
        if (row < MB) rowdot4_body(XB, WB, YB, row);
    } else {
        int row = (b - nA - nB) * 4 + wv;
        if (row < MC) rowdot4_body(XC, WC, YC, row);
    }
}

__global__ __launch_bounds__(256) void rowdot_one(const ushort* XA, const float* WA, float* YA, int MA) {
    int wv = threadIdx.x >> 6;
    int row = blockIdx.x * 4 + wv;
    if (row < MA) rowdot4_body(XA, WA, YA, row);
}

// final decoder row GEMM: out[i,0..2) = X[i,:256]@W2[256,2] + b2; out dtype per flag
__global__ __launch_bounds__(256) void rowdot_out(const ushort* __restrict__ X, const ushort* __restrict__ W2,
                                                  const ushort* __restrict__ b2, void* __restrict__ Y, int M,
                                                  const int* __restrict__ flag) {
    int wv = threadIdx.x >> 6, lane = threadIdx.x & 63;
    int row = blockIdx.x * 4 + wv;
    if (row >= M) return;
    uint2 xu = *(const uint2*)(X + (size_t)row * HIDF + lane * 4);
    float x[4] = {bf_lo(xu.x), bf_hi(xu.x), bf_lo(xu.y), bf_hi(xu.y)};
    float p0 = 0.f, p1 = 0.f;
#pragma unroll
    for (int i = 0; i < 4; ++i) {
        int k = lane * 4 + i;
        p0 += x[i] * ldb(W2 + k * 2 + 0);
        p1 += x[i] * ldb(W2 + k * 2 + 1);
    }
#pragma unroll
    for (int off = 32; off >= 1; off >>= 1) {
        p0 += __shfl_down(p0, off, 64);
        p1 += __shfl_down(p1, off, 64);
    }
    if (lane == 0) {
        float v0 = p0 + ldb(b2 + 0);
        float v1 = p1 + ldb(b2 + 1);
        if (*flag) {
            ((ushort*)Y)[(size_t)row * 2 + 0] = f2b(v0);
            ((ushort*)Y)[(size_t)row * 2 + 1] = f2b(v1);
        } else {
            ((float*)Y)[(size_t)row * 2 + 0] = v0;
            ((float*)Y)[(size_t)row * 2 + 1] = v1;
        }
    }
}

// ---------------------------------------------------------------------------
// edge pass A: a = exp(leakyrelu(el[src]+er[dst](+c*e2p))); denom[dst] += a
// ---------------------------------------------------------------------------
__global__ void edge_pass_a(const int* __restrict__ src, const int* __restrict__ dst,
                            const float* __restrict__ el, const float* __restrict__ er,
                            const ushort* __restrict__ e2p, const float* __restrict__ c1,
                            float4* __restrict__ abufv, float* __restrict__ denom, int E) {
    int e = blockIdx.x * 256 + threadIdx.x;
    if (e >= E) return;
    int s = src[e], d = dst[e];
    float ev = e2p ? ldb(e2p + e) : 0.f;
    float a[NHEAD];
#pragma unroll
    for (int h = 0; h < NHEAD; ++h) {
        float v = el[s * NHEAD + h] + er[d * NHEAD + h];
        if (e2p) v += c1[h] * ev;
        v = v > 0.f ? v : 0.2f * v;  // leaky relu
        a[h] = __expf(v);
        atomicAdd(&denom[d * NHEAD + h], a[h]);
    }
    abufv[e] = make_float4(a[0], a[1], a[2], a[3]);
}

// ---------------------------------------------------------------------------
// combined graph sort (both convs, runs once): hist -> scan -> scatter(int2)
// ---------------------------------------------------------------------------
__global__ void hist2_kernel(const int* __restrict__ dst1, const int* __restrict__ dst2,
                             int* __restrict__ cnt, int E) {
    int e = blockIdx.x * 256 + threadIdx.x;
    if (e >= E) return;
    atomicAdd(&cnt[dst1[e]], 1);
    atomicAdd(&cnt[NPP + dst2[e]], 1);
}

__global__ __launch_bounds__(1024) void scan_block(const int* __restrict__ cnt, int* __restrict__ starts,
                                                   int* __restrict__ bsum, int n) {
    __shared__ int sd[1024];
    int t = threadIdx.x, i = blockIdx.x * 1024 + t;
    int x = (i < n) ? cnt[i] : 0;
    sd[t] = x;
    __syncthreads();
    for (int o = 1; o < 1024; o <<= 1) {
        int v = (t >= o) ? sd[t - o] : 0;
        __syncthreads();
        sd[t] += v;
        __syncthreads();
    }
    if (i < n) starts[i] = sd[t] - x;  // exclusive
    if (t == 1023) bsum[blockIdx.x] = sd[t];
}

__global__ __launch_bounds__(1024) void scan_small(int* __restrict__ bsum, int nb) {
    __shared__ int sd[1024];
    int t = threadIdx.x;
    int x = (t < nb) ? bsum[t] : 0;
    sd[t] = x;
    __syncthreads();
    for (int o = 1; o < 1024; o <<= 1) {
        int v = (t >= o) ? sd[t - o] : 0;
        __syncthreads();
        sd[t] += v;
        __syncthreads();
    }
    if (t < nb) bsum[t] = sd[t] - x;  // exclusive
}

__global__ __launch_bounds__(1024) void scan_add(int* __restrict__ starts, const int* __restrict__ bsum, int n) {
    int i = blockIdx.x * 1024 + threadIdx.x;
    if (i < n) starts[i] += bsum[blockIdx.x];
}

__global__ void scatter2_kernel(const int* __restrict__ src1, const int* __restrict__ dst1,
                                const int* __restrict__ src2, const int* __restrict__ dst2,
                                const int* __restrict__ starts, int* __restrict__ fill,
                                int2* __restrict__ seg, int E) {
    int e = blockIdx.x * 256 + threadIdx.x;
    if (e >= E) return;
    int d = dst1[e];
    int p = starts[d] + atomicAdd(&fill[d], 1);
    seg[p] = make_int2(src1[e], e);
    int d2 = NPP + dst2[e];
    int p2 = starts[d2] + atomicAdd(&fill[d2], 1);
    seg[p2] = make_int2(src2[e], e);
}

// ---------------------------------------------------------------------------
// gather v4: WAVE per dst, 2-wide edge unroll.
// ---------------------------------------------------------------------------
#define FMA16(al, z0, z1)                                   \
    {                                                       \
        acc[0] += (al)*bf_lo((z0).x);  acc[1] += (al)*bf_hi((z0).x);  \
        acc[2] += (al)*bf_lo((z0).y);  acc[3] += (al)*bf_hi((z0).y);  \
        acc[4] += (al)*bf_lo((z0).z);  acc[5] += (al)*bf_hi((z0).z);  \
        acc[6] += (al)*bf_lo((z0).w);  acc[7] += (al)*bf_hi((z0).w);  \
        acc[8] += (al)*bf_lo((z1).x);  acc[9] += (al)*bf_hi((z1).x);  \
        acc[10] += (al)*bf_lo((z1).y); acc[11] += (al)*bf_hi((z1).y); \
        acc[12] += (al)*bf_lo((z1).z); acc[13] += (al)*bf_hi((z1).z); \
        acc[14] += (al)*bf_lo((z1).w); acc[15] += (al)*bf_hi((z1).w); \
    }

__global__ __launch_bounds__(256) void gather_agg(const int2* __restrict__ seg, const int* __restrict__ starts,
                                                  const float4* __restrict__ abufv, const float4* __restrict__ denomv,
                                                  const ushort* __restrict__ zs, ushort* __restrict__ aggb,
                                                  int r0, int r1, int first) {
    int wave = threadIdx.x >> 6, lane = threadIdx.x & 63;
    int d = blockIdx.x * 4 + wave;
    int h = lane >> 4;            // head this lane accumulates
    int c16 = (lane & 15) * 16;   // col base within [0,256)
    int s0 = starts[d], s1 = starts[d + 1];
    float4 dn = denomv[d];
    float rd = 0.25f / fmaxf(h == 0 ? dn.x : h == 1 ? dn.y : h == 2 ? dn.z : dn.w, 1e-9f);
    float acc[16];
#pragma unroll
    for (int j = 0; j < 16; ++j) acc[j] = 0.f;

    const size_t zoff = (size_t)h * 256 + c16;
    int i = s0;
    for (; i + 1 < s1; i += 2) {
        int2 e0 = seg[i], e1 = seg[i + 1];
        bool v0 = (e0.x >= r0) && (e0.x < r1);
        bool v1 = (e1.x >= r0) && (e1.x < r1);
        float4 a0, a1;
        uint4 p00, p01, p10, p11;
        if (v0) {
            a0 = abufv[e0.y];
            const ushort* zr = zs + (size_t)(e0.x - r0) * HD4 + zoff;
            p00 = *(const uint4*)zr;
            p01 = *(const uint4*)(zr + 8);
        }
        if (v1) {
            a1 = abufv[e1.y];
            const ushort* zr = zs + (size_t)(e1.x - r0) * HD4 + zoff;
            p10 = *(const uint4*)zr;
            p11 = *(const uint4*)(zr + 8);
        }
        if (v0) {
            float al = (h == 0 ? a0.x : h == 1 ? a0.y : h == 2 ? a0.z : a0.w) * rd;
            FMA16(al, p00, p01);
        }
        if (v1) {
            float al = (h == 0 ? a1.x : h == 1 ? a1.y : h == 2 ? a1.z : a1.w) * rd;
            FMA16(al, p10, p11);
        }
    }
    if (i < s1) {
        int2 e0 = seg[i];
        if (e0.x >= r0 && e0.x < r1) {
            float4 a0 = abufv[e0.y];
            const ushort* zr = zs + (size_t)(e0.x - r0) * HD4 + zoff;
            uint4 p00 = *(const uint4*)zr;
            uint4 p01 = *(const uint4*)(zr + 8);
            float al = (h == 0 ? a0.x : h == 1 ? a0.y : h == 2 ? a0.z : a0.w) * rd;
            FMA16(al, p00, p01);
        }
    }

#pragma unroll
    for (int j = 0; j < 16; ++j) {
        acc[j] += __shfl_xor(acc[j], 16, 64);
        acc[j] += __shfl_xor(acc[j], 32, 64);
    }

    if (h == 0) {
        size_t oi = (size_t)d * HIDF + c16;
        if (!first) {
            uint4 p0 = *(const uint4*)(aggb + oi);
            uint4 p1 = *(const uint4*)(aggb + oi + 8);
            acc[0] += bf_lo(p0.x);  acc[1] += bf_hi(p0.x);
            acc[2] += bf_lo(p0.y);  acc[3] += bf_hi(p0.y);
            acc[4] += bf_lo(p0.z);  acc[5] += bf_hi(p0.z);
            acc[6] += bf_lo(p0.w);  acc[7] += bf_hi(p0.w);
            acc[8] += bf_lo(p1.x);  acc[9] += bf_hi(p1.x);
            acc[10] += bf_lo(p1.y); acc[11] += bf_hi(p1.y);
            acc[12] += bf_lo(p1.z); acc[13] += bf_hi(p1.z);
            acc[14] += bf_lo(p1.w); acc[15] += bf_hi(p1.w);
        }
        uint uo[8];
#pragma unroll
        for (int j = 0; j < 8; ++j)
            uo[j] = (uint)f2b(acc[2 * j]) | ((uint)f2b(acc[2 * j + 1]) << 16);
        *(uint4*)(aggb + oi) = make_uint4(uo[0], uo[1], uo[2], uo[3]);
        *(uint4*)(aggb + oi + 8) = make_uint4(uo[4], uo[5], uo[6], uo[7]);
    }
}

// ---------------------------------------------------------------------------
extern "C" void kernel_launch(void* const* d_in, const int* in_sizes, int n_in,
                              void* d_out, int out_size, void* d_ws, size_t ws_size,
                              hipStream_t stream) {
    const int* src1 = (const int*)d_in[26];
    const int* dst1 = (const int*)d_in[27];
    const int* src2 = (const int*)d_in[28];
    const int* dst2 = (const int*)d_in[29];

    static const int csz[N_CVT] = {
        N_LINK * 8, N_FLOW * 16, N_PATH * 8, NEDGE,
        8 * 256, 256, 16 * 256, 256, 8 * 256, 256,
        256 * 1024, 256 * 1024, 1024, 1024, 1024, 1024,
        256 * 256, 256 * 1024, 256 * 1024, 1024, 1024, 256 * 256,
        768 * 256, 256, 256 * 2, 2};

    // ---- workspace layout (bytes, 256B-aligned slots) ----
    char* base = (char*)d_ws;
    size_t off = 0;
    auto alloc = [&](size_t bytes) { size_t r = off; off += (bytes + 255) & ~255ull; return r; };

    size_t o_flag = alloc(256);
    CvtArgs ca;
    int coff[N_CVT];
    {
        int acc = 0;
        for (int i = 0; i < N_CVT; ++i) {
            ca.src[i] = d_in[i];
            ca.sz[i] = csz[i];
            ca.off[i] = acc;
            coff[i] = acc;
            acc += (csz[i] + 127) & ~127;
        }
        alloc((size_t)acc * 2);
    }
    const ushort* cvt = (const ushort*)(base + o_flag + 256);
    auto IN = [&](int i) { return cvt + coff[i]; };

    size_t o_h_link  = alloc((size_t)N_LINK * HIDF * 2);
    size_t o_h_flow  = alloc((size_t)N_FLOW * HIDF * 2);
    size_t o_h_path0 = alloc((size_t)N_PATH * HIDF * 2);  // reused as 'hidden'
    size_t o_h1      = alloc((size_t)N_PATH * HIDF * 2);
    size_t o_h2      = alloc((size_t)N_PATH * HIDF * 2);
    size_t o_aggb    = alloc((size_t)N_PATH * HIDF * 2);  // bf16 gather target
    size_t o_el      = alloc((size_t)N_LINK * NHEAD * 4);
    size_t o_el2     = alloc((size_t)N_FLOW * NHEAD * 4);
    size_t o_er      = alloc((size_t)N_PATH * NHEAD * 4);
    size_t o_abuf    = alloc((size_t)NEDGE * NHEAD * 4);
    // contiguous zero-region: denom1 + denom2 + cnt + fill (one memset)
    size_t o_denom1  = alloc((size_t)N_PATH * NHEAD * 4);
    size_t o_denom2  = alloc((size_t)N_PATH * NHEAD * 4);
    size_t o_cnt     = alloc((size_t)NSCAN * 4);
    size_t o_fill    = alloc((size_t)NSCAN * 4);
    size_t zero_span = o_fill + (size_t)NSCAN * 4 - o_denom1;
    size_t o_wl1 = alloc(HIDF * NHEAD * 4);
    size_t o_wr1 = alloc(HIDF * NHEAD * 4);
    size_t o_wl2 = alloc(HIDF * NHEAD * 4);
    size_t o_wr2 = alloc(HIDF * NHEAD * 4);
    size_t o_c1  = alloc(NHEAD * 4);
    size_t o_bt_src1 = alloc((size_t)HD4 * HIDF * 2);
    size_t o_bt_src2 = alloc((size_t)HD4 * HIDF * 2);
    size_t o_bt_rw1  = alloc((size_t)HIDF * HIDF * 2);
    size_t o_bt_rw2  = alloc((size_t)HIDF * HIDF * 2);
    size_t o_bt_w1ac = alloc((size_t)HIDF * HIDF * 2);
    size_t o_bt_w1b  = alloc((size_t)HIDF * HIDF * 2);
    size_t o_starts = alloc((size_t)(NSCAN + 1) * 4);
    size_t o_seg    = alloc((size_t)(2 * NEDGE) * 8);
    size_t o_bsum   = alloc(1024 * 4);
    size_t o_zs = off;  // adaptive chunk buffer takes the rest

    int* flag = (int*)(base + o_flag);

    long avail = (long)ws_size - (long)off;
    long Rl = avail / (HD4 * 2);
    int R = (int)(Rl > N_FLOW ? N_FLOW : Rl);
    R &= ~63;
    detect_dtype<<<1, 64, 0, stream>>>((const ushort*)d_in[13], flag);
    if (R < 256) {
        sentinel_fill<<<(out_size + 255) / 256, 256, 0, stream>>>(d_out, out_size,
                                                                  (float)(ws_size >> 20), flag);
        return;
    }

    ushort* h_link = (ushort*)(base + o_h_link);
    ushort* h_flow = (ushort*)(base + o_h_flow);
    ushort* h_path0 = (ushort*)(base + o_h_path0);
    ushort* h1 = (ushort*)(base + o_h1);
    ushort* h2 = (ushort*)(base + o_h2);
    ushort* zs = (ushort*)(base + o_zs);
    ushort* aggb = (ushort*)(base + o_aggb);
    float* el = (float*)(base + o_el);
    float* el2 = (float*)(base + o_el2);
    float* er = (float*)(base + o_er);
    float* abuf = (float*)(base + o_abuf);
    float* denom1 = (float*)(base + o_denom1);
    float* denom2 = (float*)(base + o_denom2);
    int* cnt = (int*)(base + o_cnt);
    int* fill = (int*)(base + o_fill);
    float* wl1 = (float*)(base + o_wl1);
    float* wr1 = (float*)(base + o_wr1);
    float* wl2 = (float*)(base + o_wl2);
    float* wr2 = (float*)(base + o_wr2);
    float* c1 = (float*)(base + o_c1);
    ushort* bt_src1 = (ushort*)(base + o_bt_src1);
    ushort* bt_src2 = (ushort*)(base + o_bt_src2);
    ushort* bt_rw1 = (ushort*)(base + o_bt_rw1);
    ushort* bt_rw2 = (ushort*)(base + o_bt_rw2);
    ushort* bt_w1ac = (ushort*)(base + o_bt_w1ac);
    ushort* bt_w1b = (ushort*)(base + o_bt_w1b);
    int* starts = (int*)(base + o_starts);
    int2* seg = (int2*)(base + o_seg);
    int* bsum = (int*)(base + o_bsum);

    const int EB = (NEDGE + 255) / 256;

    // ---- zero denoms + cnt + fill; graph sort (depends only on edge lists) ----
    hipMemsetAsync(denom1, 0, zero_span, stream);
    hist2_kernel<<<EB, 256, 0, stream>>>(dst1, dst2, cnt, NEDGE);
    scan_block<<<NB2, 1024, 0, stream>>>(cnt, starts, bsum, NSCAN);
    scan_small<<<1, 1024, 0, stream>>>(bsum, NB2);
    scan_add<<<NB2, 1024, 0, stream>>>(starts, bsum, NSCAN);
    scatter2_kernel<<<EB, 256, 0, stream>>>(src1, dst1, src2, dst2, starts, fill, seg, NEDGE);

    // ---- convert inputs + prep ----
    convert_inputs<<<dim3((N_FLOW * 16 + 255) / 256, N_CVT), 256, 0, stream>>>(
        ca, (ushort*)(base + o_flag + 256), flag);
    PrepArgs pa;
    pa.fc[0] = IN(10); pa.at[0] = IN(13); pa.out[0] = wl1;
    pa.fc[1] = IN(11); pa.at[1] = IN(14); pa.out[1] = wr1;
    pa.fc[2] = IN(17); pa.at[2] = IN(19); pa.out[2] = wl2;
    pa.fc[3] = IN(18); pa.at[3] = IN(20); pa.out[3] = wr2;
    pa.fc[4] = IN(12); pa.at[4] = IN(15); pa.out[4] = c1;
    prep_fold<<<1025, 256, 0, stream>>>(pa);
    TJobs tj;
    tj.s1[0] = IN(10); tj.s2[0] = nullptr;            tj.d[0] = bt_src1; tj.K[0] = HIDF; tj.N[0] = HD4;
    tj.s1[1] = IN(17); tj.s2[1] = nullptr;            tj.d[1] = bt_src2; tj.K[1] = HIDF; tj.N[1] = HD4;
    tj.s1[2] = IN(16); tj.s2[2] = nullptr;            tj.d[2] = bt_rw1;  tj.K[2] = HIDF; tj.N[2] = HIDF;
    tj.s1[3] = IN(21); tj.s2[3] = nullptr;            tj.d[3] = bt_rw2;  tj.K[3] = HIDF; tj.N[3] = HIDF;
    tj.s1[4] = IN(22); tj.s2[4] = IN(22) + 512 * 256; tj.d[4] = bt_w1ac; tj.K[4] = HIDF; tj.N[4] = HIDF;
    tj.s1[5] = IN(22) + 256 * 256; tj.s2[5] = nullptr; tj.d[5] = bt_w1b; tj.K[5] = HIDF; tj.N[5] = HIDF;
    transpose_batch<<<dim3(256, 6), 256, 0, stream>>>(tj);

    proj_all<<<N_LINK / 8 + N_FLOW / 8 + N_PATH / 8, 256, 0, stream>>>(
        IN(0), IN(4), IN(5), h_link, IN(1), IN(6), IN(7), h_flow, IN(2), IN(8), IN(9), h_path0);

    ushort* hidden = h_path0;  // reuse after conv1

    // conv1-el, conv1-er, conv2-el all depend only on proj outputs
    rowdot_tri<<<(N_LINK + 3) / 4 + (N_PATH + 3) / 4 + (N_FLOW + 3) / 4, 256, 0, stream>>>(
        h_link, wl1, el, N_LINK, h_path0, wr1, er, N_PATH, h_flow, wl2, el2, N_FLOW);

    // ================= conv1: link -> path =================
    edge_pass_a<<<EB, 256, 0, stream>>>(src1, dst1, el, er, IN(3), c1, (float4*)abuf, denom1, NEDGE);
    for (int r0 = 0; r0 < N_LINK; r0 += R) {
        int r1 = r0 + R < N_LINK ? r0 + R : N_LINK;
        gemm_mfma<<<dim3(HD4 / GTN, (r1 - r0 + GTM - 1) / GTM), 256, 0, stream>>>(
            h_link + (size_t)r0 * HIDF, bt_src1, HIDF, nullptr, nullptr, 0,
            nullptr, nullptr, 0, zs, r1 - r0, HD4);
        gather_agg<<<N_PATH / 4, 256, 0, stream>>>(seg, starts, (const float4*)abuf, (const float4*)denom1,
                                                   zs, aggb, r0, r1, r0 == 0);
    }
    gemm_mfma64<<<dim3(HIDF / 64, (N_PATH + 63) / 64), 256, 0, stream>>>(
        h_path0, bt_rw1, HIDF, nullptr, nullptr, 0, aggb, nullptr, 1, h1, N_PATH, HIDF);

    // ================= conv2: flow -> path =================
    rowdot_one<<<(N_PATH + 3) / 4, 256, 0, stream>>>(h1, wr2, er, N_PATH);
    edge_pass_a<<<EB, 256, 0, stream>>>(src2, dst2, el2, er, nullptr, nullptr, (float4*)abuf, denom2, NEDGE);
    for (int r0 = 0; r0 < N_FLOW; r0 += R) {
        int r1 = r0 + R < N_FLOW ? r0 + R : N_FLOW;
        gemm_mfma<<<dim3(HD4 / GTN, (r1 - r0 + GTM - 1) / GTM), 256, 0, stream>>>(
            h_flow + (size_t)r0 * HIDF, bt_src2, HIDF, nullptr, nullptr, 0,
            nullptr, nullptr, 0, zs, r1 - r0, HD4);
        gather_agg<<<N_PATH / 4, 256, 0, stream>>>(seg, starts + NPP, (const float4*)abuf, (const float4*)denom2,
                                                   zs, aggb, r0, r1, r0 == 0);
    }
    gemm_mfma64<<<dim3(HIDF / 64, (N_PATH + 63) / 64), 256, 0, stream>>>(
        h1, bt_rw2, HIDF, nullptr, nullptr, 0, aggb, nullptr, 1, h2, N_PATH, HIDF);

    // ---- decoder ----
    gemm_mfma64<<<dim3(HIDF / 64, (N_PATH + 63) / 64), 256, 0, stream>>>(
        h2, bt_w1ac, HIDF, h1, bt_w1b, HIDF, nullptr, IN(23), 1, hidden, N_PATH, HIDF);
    rowdot_out<<<(N_PATH + 3) / 4, 256, 0, stream>>>(hidden, IN(24), IN(25), d_out, N_PATH, flag);
}